// Round 3
// baseline (457.411 us; speedup 1.0000x reference)
//
#include <hip/hip_runtime.h>
#include <hip/hip_bf16.h>
#include <math.h>

// Fused conv3x3(64->64) + bias + min_k + tanh(tanh()) via bf16 MFMA implicit GEMM.
// x: [16,64,256,256] f32, w: [64,64,3,3] f32, b: [64] f32, out: [16,1,256,256] f32
//
// Round 9: single-stage structure (latency-exposure halving).
//   r8 post-mortem: spills fixed (WRITE 473->4 MB), occupancy 21->31%, but time
//   only 200->188 us and MfmaUtil stuck at 16.7% -> latency-bound on the serial
//   stage->barrier->compute sequence, paid TWICE per block (once per 32-c chunk).
//   This round:
//   - ONE 64-c stage: sA[18 rows][20 px][72 slots] = 51.8 KB (64 c + 8 pad),
//     3 blocks/CU = 155.5 KB LDS. ONE barrier per block instead of two.
//   - Staging issues ALL thread loads (2-3 slots x 8 planes) into v[3][8] regs
//     BEFORE any ds_write -> ~24 loads in flight per thread (full MLP), vs
//     r8's per-slot load-wait-write.
//   - Compute: 9 taps x 2 k-chunks x 16 MFMA; B-frags from global (L2-hot, r8-
//     verified); A-frag k-chunk selects c 0-31 / 32-63 via +kc*32 LDS offset.
//   - KEPT: XCD-aware bijective block remap, __launch_bounds__(256,3).
// mfma_f32_16x16x32_bf16: A[m=lane&15][k=(lane>>4)*8+j], B[k=(lane>>4)*8+j][n=lane&15],
//                         C/D col=lane&15, row=(lane>>4)*4+reg (HW-verified r2-r8).

typedef __bf16 bf16x8 __attribute__((ext_vector_type(8)));
typedef float f32x4 __attribute__((ext_vector_type(4)));

#define WB_ELEMS (64 * 64 * 9)
#define SA_PX   72                      // elements per pixel slot (64 used + 8 pad)
#define SA_ROW  (20 * SA_PX)            // 1440 elements per row (20 px)

// ---- weight prep: w[k][c][tap] -> wB[(((chunk*9+tap)*4+nt)*64+lane)*8+j] ----
__global__ __launch_bounds__(256)
void conv_prep_w(const float* __restrict__ w, __bf16* __restrict__ wB) {
    int idx = blockIdx.x * 256 + threadIdx.x;
    if (idx >= WB_ELEMS) return;
    int k   = idx / 576;
    int rem = idx - k * 576;
    int c   = rem / 9;
    int tap = rem - c * 9;
    int nt = k >> 4, m15 = k & 15;
    int chunk = c >> 5, q = (c >> 3) & 3, j = c & 7;
    int lane = (q << 4) | m15;
    wB[((((chunk * 9 + tap) * 4 + nt) * 64 + lane) << 3) + j] = (__bf16)w[idx];
}

// ---- fused: stage(global fp32 -> LDS bf16, transposed) + MFMA + min/tanh epilogue ----
__global__ __launch_bounds__(256, 3)
void conv_min_tanh_fused(const float* __restrict__ x,
                         const __bf16* __restrict__ wB,
                         const float* __restrict__ b,
                         float* __restrict__ out)
{
    __shared__ __attribute__((aligned(16))) __bf16 sA[18 * SA_ROW];     // 51840 B

    const int tid  = threadIdx.x;
    const int lane = tid & 63;
    const int wave = tid >> 6;
    const int m15  = lane & 15;
    const int q    = lane >> 4;

    // XCD-aware bijective remap of the 4096-block grid (8 XCDs x 512 tiles):
    // hw block b lands on XCD b%8; give each XCD a contiguous tile range so
    // w/h-neighbor tiles (which share halo cache lines) hit the same L2.
    const int lin = (int)blockIdx.x + ((int)blockIdx.y << 4) + ((int)blockIdx.z << 8);
    const int nl  = ((lin & 7) << 9) | (lin >> 3);
    const int n   = nl >> 8;
    const int h0  = ((nl >> 4) & 15) << 4;
    const int w0  = (nl & 15) << 4;

    // ---- stage A: halo rows h0-1..h0+16, px w0-1..w0+18, ALL 64 c ----
    // slot = row*40 + span*8 + cg ; slot covers 4 px (span) x 8 c (cg*8..+7).
    // 720 slots over 256 threads: it=0,1 always valid, it=2 only tid<208.
    // Phase 1: issue ALL loads (up to 24 in flight). Phase 2: convert + ds_write.
    f32x4 v[3][8];
#pragma unroll
    for (int it = 0; it < 3; ++it) {
        const int slot = tid + it * 256;
        if (it == 2 && slot >= 720) continue;
        const int row  = slot / 40;
        const int rem  = slot - row * 40;
        const int span = rem >> 3;
        const int cg   = rem & 7;
        const int gh   = h0 + row - 1;
        const int gw0  = w0 - 1 + span * 4;
        if ((unsigned)gh < 256u) {
            const float* src = x + (size_t)(n * 64 + cg * 8) * 65536
                                 + (size_t)gh * 256;
            if (gw0 >= 0 && gw0 <= 252) {
#pragma unroll
                for (int j = 0; j < 8; ++j)
                    v[it][j] = *(const f32x4*)&src[(size_t)j * 65536 + gw0];
            } else {
#pragma unroll
                for (int j = 0; j < 8; ++j)
#pragma unroll
                    for (int i = 0; i < 4; ++i) {
                        const int gw = gw0 + i;
                        v[it][j][i] = ((unsigned)gw < 256u) ? src[(size_t)j * 65536 + gw] : 0.f;
                    }
            }
        } else {
#pragma unroll
            for (int j = 0; j < 8; ++j)
                v[it][j] = (f32x4){0.f, 0.f, 0.f, 0.f};
        }
    }
#pragma unroll
    for (int it = 0; it < 3; ++it) {
        const int slot = tid + it * 256;
        if (it == 2 && slot >= 720) continue;
        const int row  = slot / 40;
        const int rem  = slot - row * 40;
        const int span = rem >> 3;
        const int cg   = rem & 7;
        __bf16* wp = &sA[row * SA_ROW + (span * 4) * SA_PX + cg * 8];
#pragma unroll
        for (int i = 0; i < 4; ++i) {
            bf16x8 o;
            o[0] = (__bf16)v[it][0][i]; o[1] = (__bf16)v[it][1][i];
            o[2] = (__bf16)v[it][2][i]; o[3] = (__bf16)v[it][3][i];
            o[4] = (__bf16)v[it][4][i]; o[5] = (__bf16)v[it][5][i];
            o[6] = (__bf16)v[it][6][i]; o[7] = (__bf16)v[it][7][i];
            *(bf16x8*)&wp[i * SA_PX] = o;
        }
    }
    __syncthreads();

    // ---- compute: 9 taps x 2 k-chunks; A from LDS, B from global (L2-hot) ----
    f32x4 acc[4][4];  // [mt][nt]
#pragma unroll
    for (int mt = 0; mt < 4; ++mt)
#pragma unroll
        for (int nt = 0; nt < 4; ++nt)
            acc[mt][nt] = (f32x4){0.f, 0.f, 0.f, 0.f};

#pragma unroll
    for (int r = 0; r < 3; ++r) {
#pragma unroll
        for (int s = 0; s < 3; ++s) {
            const int tap = r * 3 + s;
#pragma unroll
            for (int kc = 0; kc < 2; ++kc) {
                const __bf16* wBc = wB + kc * 18432;
                bf16x8 bf[4], a4[4];
#pragma unroll
                for (int nt = 0; nt < 4; ++nt)
                    bf[nt] = *(const bf16x8*)&wBc[(((tap << 2) | nt) << 9) | (lane << 3)];
#pragma unroll
                for (int mt = 0; mt < 4; ++mt)
                    a4[mt] = *(const bf16x8*)
                        &sA[(wave * 4 + mt + r) * SA_ROW + (m15 + s) * SA_PX + kc * 32 + q * 8];
#pragma unroll
                for (int mt = 0; mt < 4; ++mt)
#pragma unroll
                    for (int nt = 0; nt < 4; ++nt)
                        acc[mt][nt] = __builtin_amdgcn_mfma_f32_16x16x32_bf16(
                            a4[mt], bf[nt], acc[mt][nt], 0, 0, 0);
            }
        }
    }

    // ---- epilogue: +bias, min over 64 k, tanh(tanh), store (verified r2-r8) ----
    float bias[4];
#pragma unroll
    for (int nt = 0; nt < 4; ++nt) bias[nt] = b[nt * 16 + m15];

#pragma unroll
    for (int mt = 0; mt < 4; ++mt) {
        float mv[4];
#pragma unroll
        for (int reg = 0; reg < 4; ++reg) {
            float v2 = acc[mt][0][reg] + bias[0];
            v2 = fminf(v2, acc[mt][1][reg] + bias[1]);
            v2 = fminf(v2, acc[mt][2][reg] + bias[2]);
            v2 = fminf(v2, acc[mt][3][reg] + bias[3]);
            v2 = fminf(v2, __shfl_xor(v2, 1));
            v2 = fminf(v2, __shfl_xor(v2, 2));
            v2 = fminf(v2, __shfl_xor(v2, 4));
            v2 = fminf(v2, __shfl_xor(v2, 8));
            mv[reg] = v2;
        }
        const int r2 = lane & 3;
        float v2 = mv[0];
        v2 = (r2 == 1) ? mv[1] : v2;
        v2 = (r2 == 2) ? mv[2] : v2;
        v2 = (r2 == 3) ? mv[3] : v2;
        v2 = tanhf(tanhf(v2));
        if (m15 < 4) {
            const int pix = q * 4 + r2;
            const int gh  = h0 + wave * 4 + mt;
            const int gw  = w0 + pix;
            out[((size_t)n * 256 + gh) * 256 + gw] = v2;
        }
    }
}

extern "C" void kernel_launch(void* const* d_in, const int* in_sizes, int n_in,
                              void* d_out, int out_size, void* d_ws, size_t ws_size,
                              hipStream_t stream) {
    const float* x = (const float*)d_in[0];
    const float* w = (const float*)d_in[1];
    const float* b = (const float*)d_in[2];
    float* out = (float*)d_out;
    __bf16* wB = (__bf16*)d_ws;  // 73728 B

    conv_prep_w<<<dim3(144), dim3(256), 0, stream>>>(w, wB);
    conv_min_tanh_fused<<<dim3(16, 16, 16), dim3(256), 0, stream>>>(x, wB, b, out);
}